// Round 5
// baseline (242.120 us; speedup 1.0000x reference)
//
#include <hip/hip_runtime.h>
#include <hip/hip_bf16.h>

typedef __bf16 bf16_t;
typedef __attribute__((ext_vector_type(4))) __bf16 bf16x4;
typedef __attribute__((ext_vector_type(8))) __bf16 bf16x8;
typedef __attribute__((ext_vector_type(4))) float f32x4;

#define NEGV (-1e30f)

// Problem constants
#define BB 4
#define TT 200
#define UU 50
#define U1 51
#define VV 1024
#define DD 512
#define HH 640
#define RTOT (BB*TT*U1)      // 40800
#define RPAD 40832           // 638*64
#define SS 101

__device__ __forceinline__ float lae(float a, float b) {
    float mx = fmaxf(a, b);
    return mx + __logf(__expf(a - mx) + __expf(b - mx));
}
__device__ __forceinline__ float lae3(float a, float b, float c) {
    float mx = fmaxf(fmaxf(a, b), c);
    return mx + __logf(__expf(a - mx) + __expf(b - mx) + __expf(c - mx));
}
__device__ __forceinline__ float tanh_fast(float x) {
    float ex = __expf(2.f * x);
    return 1.f - 2.f / (ex + 1.f);
}

// ---------------- pack fp32 (K x N) weight into bf16 MFMA B-fragment order.
__device__ __forceinline__ void pack_seg(const float* __restrict__ W, bf16_t* __restrict__ Wf,
                                         int e, int K32, int N)
{
    int j  = e & 7;
    int l  = (e >> 3) & 63;
    int kk = (e >> 9) % K32;
    int nt = e / (K32 * 512);
    int v = nt * 16 + (l & 15);
    int k = kk * 32 + ((l >> 4) << 2) + (j & 3) + ((j >> 2) << 4);
    Wf[e] = (bf16_t)W[(size_t)k * N + v];
}

__global__ void pack_all(const float* __restrict__ Wout, const float* __restrict__ Wenc,
                         const float* __restrict__ Wpred, const float* __restrict__ Wctc,
                         bf16_t* __restrict__ FOut, bf16_t* __restrict__ FEnc,
                         bf16_t* __restrict__ FPred, bf16_t* __restrict__ FCtc)
{
    int e = blockIdx.x * 256 + threadIdx.x;
    if (e < 655360) { pack_seg(Wout, FOut, e, 20, 1024); return; }
    e -= 655360;
    if (e < 327680) { pack_seg(Wenc, FEnc, e, 16, 640); return; }
    e -= 327680;
    if (e < 409600) { pack_seg(Wpred, FPred, e, 20, 640); return; }
    e -= 409600;
    pack_seg(Wctc, FCtc, e, 16, 1024);
}

// ---------------- generic MFMA GEMM: C = A(MxK fp32) @ Wf(packed bf16) -----
template<int K32, int L, bool LSE>
__device__ void gemm_dev(const float* __restrict__ A, int M, int rowbase, int K,
                         const bf16_t* __restrict__ Wf, const float* __restrict__ bias,
                         float* __restrict__ C, float* __restrict__ lse_out, int N,
                         bf16_t* Atile, float (*ps)[8])
{
    const int tid = threadIdx.x;
    // build A tile (64 x K) in fragment order; thread == fragment -> contiguous
    // 16B LDS writes (conflict-free ds_write_b128). Total fragments =
    // 4*K32*64 = 256*K32 -> K32/2 iterations of 512 threads.
#pragma unroll
    for (int it = 0; it < K32 / 2; ++it) {
        int fi = it * 512 + tid;
        int l = fi & 63, jk = fi >> 6;
        int j = jk / K32, kk = jk - j * K32;
        int row = rowbase + j * 16 + (l & 15);
        if (row > M - 1) row = M - 1;
        int c0 = kk * 32 + ((l >> 4) << 2);
        const float4 a0 = *(const float4*)&A[(size_t)row * K + c0];
        const float4 a1 = *(const float4*)&A[(size_t)row * K + c0 + 16];
        bf16x8 v;
        v[0] = (bf16_t)a0.x; v[1] = (bf16_t)a0.y; v[2] = (bf16_t)a0.z; v[3] = (bf16_t)a0.w;
        v[4] = (bf16_t)a1.x; v[5] = (bf16_t)a1.y; v[6] = (bf16_t)a1.z; v[7] = (bf16_t)a1.w;
        *(bf16x8*)&Atile[(size_t)fi * 8] = v;
    }
    __syncthreads();

    const int l = tid & 63, w = tid >> 6;
    const int lrow = l & 15, lhi = l >> 4;

    f32x4 acc[4][L];
#pragma unroll
    for (int j = 0; j < 4; ++j)
#pragma unroll
        for (int li = 0; li < L; ++li) acc[j][li] = f32x4{0.f, 0.f, 0.f, 0.f};

#pragma unroll
    for (int kk = 0; kk < K32; ++kk) {
        bf16x8 a[4];
#pragma unroll
        for (int j = 0; j < 4; ++j)
            a[j] = *(const bf16x8*)&Atile[(size_t)(((j * K32 + kk) * 64 + l) * 8)];
#pragma unroll
        for (int li = 0; li < L; ++li) {
            bf16x8 b = *(const bf16x8*)&Wf[(size_t)(((w * L + li) * K32 + kk) * 64 + l) * 8];
#pragma unroll
            for (int j = 0; j < 4; ++j)
                acc[j][li] = __builtin_amdgcn_mfma_f32_16x16x32_bf16(a[j], b, acc[j][li], 0, 0, 0);
        }
    }

    float se[4][4];
    if (LSE) {
#pragma unroll
        for (int j = 0; j < 4; ++j)
#pragma unroll
            for (int i = 0; i < 4; ++i) se[j][i] = 0.f;
    }
#pragma unroll
    for (int j = 0; j < 4; ++j)
#pragma unroll
        for (int li = 0; li < L; ++li) {
            int col = (w * L + li) * 16 + lrow;
            float bv = bias ? bias[col] : 0.f;
#pragma unroll
            for (int i = 0; i < 4; ++i) {
                int grow = rowbase + 16 * j + lhi * 4 + i;
                float x = acc[j][li][i] + bv;
                if (grow < M) C[(size_t)grow * N + col] = x;
                if (LSE) se[j][i] += __expf(x);
            }
        }
    if (LSE) {
#pragma unroll
        for (int d = 1; d < 16; d <<= 1)
#pragma unroll
            for (int j = 0; j < 4; ++j)
#pragma unroll
                for (int i = 0; i < 4; ++i) se[j][i] += __shfl_xor(se[j][i], d);
        if (lrow == 0) {
#pragma unroll
            for (int j = 0; j < 4; ++j)
#pragma unroll
                for (int i = 0; i < 4; ++i) ps[16 * j + lhi * 4 + i][w] = se[j][i];
        }
        __syncthreads();
        if (tid < 64) {
            float s = 0.f;
#pragma unroll
            for (int w0 = 0; w0 < 8; ++w0) s += ps[tid][w0];
            int grow = rowbase + tid;
            if (grow < M) lse_out[grow] = __logf(s);
        }
    }
}

__global__ __launch_bounds__(512)
void mfma_gemm3(const float* __restrict__ x_enc, const float* __restrict__ x_dec,
                const bf16_t* __restrict__ FEnc, const bf16_t* __restrict__ FPred,
                const bf16_t* __restrict__ FCtc, const float* __restrict__ b_ctc,
                float* __restrict__ enc_proj, float* __restrict__ pred_proj,
                float* __restrict__ ctc_logits, float* __restrict__ ctc_lse)
{
    __shared__ bf16_t Atile[40960];
    __shared__ float ps[64][8];
    int blk = blockIdx.x;
    if (blk < 13)
        gemm_dev<16, 5, false>(x_enc, 800, blk * 64, 512, FEnc, nullptr, enc_proj, nullptr, 640, Atile, ps);
    else if (blk < 17)
        gemm_dev<20, 5, false>(x_dec, 204, (blk - 13) * 64, 640, FPred, nullptr, pred_proj, nullptr, 640, Atile, ps);
    else
        gemm_dev<16, 8, true>(x_enc, 800, (blk - 17) * 64, 512, FCtc, b_ctc, ctc_logits, ctc_lse, 1024, Atile, ps);
}

// ---------------- fused joint build + MFMA GEMM + row-LSE + gather ---------
__global__ __launch_bounds__(512, 2)
void joint_gemm(const float* __restrict__ enc,   // (800,640)
                const float* __restrict__ pred,  // (204,640)
                const float* __restrict__ bj,    // (640)
                const bf16_t* __restrict__ Wf,   // packed (K32=20, NT=64)
                const float* __restrict__ bo,    // (1024)
                const int* __restrict__ target,  // (4,50)
                float* __restrict__ blank_buf, float* __restrict__ emit_buf)
{
    __shared__ bf16_t Afrag[40960];              // 64 rows x 640 K, frag order
    __shared__ int rowBT[64], rowBU[64], rowTG[64];
    __shared__ float ps[64][8], pe[64][8], pb[64][8];
    const int tid = threadIdx.x;
    const int blk = blockIdx.x;

    const int l = tid & 63, w = tid >> 6;
    const int lrow = l & 15, lhi = l >> 4;

    if (tid < 64) {
        int r = blk * 64 + tid; if (r > RTOT - 1) r = RTOT - 1;
        int b = r / (TT * U1); int rem = r - b * (TT * U1);
        int t = rem / U1;      int u = rem - t * U1;
        rowBT[tid] = b * TT + t;
        rowBU[tid] = b * U1 + u;
        rowTG[tid] = (u < UU) ? target[b * UU + u] : -1;
    }

    // kk=0 B-fragments: independent of LDS -> issue before the A build so the
    // loads cover the whole build phase.
    const bf16_t* Bp = &Wf[(size_t)((w * 8 * 20) * 64 + l) * 8];
    bf16x8 bC[8], bN[8];
#pragma unroll
    for (int li = 0; li < 8; ++li) bC[li] = *(const bf16x8*)(Bp + (size_t)li * 10240);

    __syncthreads();

    // build tanh(enc+pred+bj) tile; thread == fragment -> contiguous 16B
    // LDS writes (conflict-free). 5120 fragments / 512 threads = 10 iters.
#pragma unroll
    for (int it = 0; it < 10; ++it) {
        int fi = it * 512 + tid;
        int ll = fi & 63, jk = fi >> 6;
        int j = jk / 20, kk = jk - j * 20;
        int row = j * 16 + (ll & 15);
        int c0 = kk * 32 + ((ll >> 4) << 2);
        const float4 e0 = *(const float4*)&enc[(size_t)rowBT[row] * HH + c0];
        const float4 e1 = *(const float4*)&enc[(size_t)rowBT[row] * HH + c0 + 16];
        const float4 p0 = *(const float4*)&pred[(size_t)rowBU[row] * HH + c0];
        const float4 p1 = *(const float4*)&pred[(size_t)rowBU[row] * HH + c0 + 16];
        const float4 q0 = *(const float4*)&bj[c0];
        const float4 q1 = *(const float4*)&bj[c0 + 16];
        bf16x8 v;
        v[0] = (bf16_t)tanh_fast(e0.x + p0.x + q0.x);
        v[1] = (bf16_t)tanh_fast(e0.y + p0.y + q0.y);
        v[2] = (bf16_t)tanh_fast(e0.z + p0.z + q0.z);
        v[3] = (bf16_t)tanh_fast(e0.w + p0.w + q0.w);
        v[4] = (bf16_t)tanh_fast(e1.x + p1.x + q1.x);
        v[5] = (bf16_t)tanh_fast(e1.y + p1.y + q1.y);
        v[6] = (bf16_t)tanh_fast(e1.z + p1.z + q1.z);
        v[7] = (bf16_t)tanh_fast(e1.w + p1.w + q1.w);
        *(bf16x8*)&Afrag[(size_t)fi * 8] = v;
    }
    __syncthreads();

    f32x4 acc[4][8];
#pragma unroll
    for (int j = 0; j < 4; ++j)
#pragma unroll
        for (int li = 0; li < 8; ++li) acc[j][li] = f32x4{0.f, 0.f, 0.f, 0.f};

    // K loop: B double-buffered in registers, A read just-in-time from LDS
#pragma unroll
    for (int kk = 0; kk < 20; ++kk) {
        if (kk < 19) {
#pragma unroll
            for (int li = 0; li < 8; ++li)
                bN[li] = *(const bf16x8*)(Bp + (size_t)(kk + 1) * 512 + (size_t)li * 10240);
        }
        bf16x8 a[4];
#pragma unroll
        for (int j = 0; j < 4; ++j)
            a[j] = *(const bf16x8*)&Afrag[(size_t)(((j * 20 + kk) * 64 + l) * 8)];
#pragma unroll
        for (int li = 0; li < 8; ++li)
#pragma unroll
            for (int j = 0; j < 4; ++j)
                acc[j][li] = __builtin_amdgcn_mfma_f32_16x16x32_bf16(a[j], bC[li], acc[j][li], 0, 0, 0);
#pragma unroll
        for (int li = 0; li < 8; ++li) bC[li] = bN[li];
    }

    int tg[4][4];
#pragma unroll
    for (int j = 0; j < 4; ++j)
#pragma unroll
        for (int i = 0; i < 4; ++i) tg[j][i] = rowTG[16 * j + lhi * 4 + i];

    float se[4][4], ee[4][4], bbv[4][4];
#pragma unroll
    for (int j = 0; j < 4; ++j)
#pragma unroll
        for (int i = 0; i < 4; ++i) { se[j][i] = 0.f; ee[j][i] = NEGV; bbv[j][i] = NEGV; }

#pragma unroll
    for (int li = 0; li < 8; ++li) {
        int col = (w * 8 + li) * 16 + lrow;
        float bv = bo[col];
#pragma unroll
        for (int j = 0; j < 4; ++j)
#pragma unroll
            for (int i = 0; i < 4; ++i) {
                float x = acc[j][li][i] + bv;
                se[j][i] += __expf(x);
                if (col == tg[j][i]) ee[j][i] = x;
                if (col == VV - 1) bbv[j][i] = x;
            }
    }
#pragma unroll
    for (int d = 1; d < 16; d <<= 1)
#pragma unroll
        for (int j = 0; j < 4; ++j)
#pragma unroll
            for (int i = 0; i < 4; ++i) {
                se[j][i] += __shfl_xor(se[j][i], d);
                ee[j][i] = fmaxf(ee[j][i], __shfl_xor(ee[j][i], d));
                bbv[j][i] = fmaxf(bbv[j][i], __shfl_xor(bbv[j][i], d));
            }
    if (lrow == 0) {
#pragma unroll
        for (int j = 0; j < 4; ++j)
#pragma unroll
            for (int i = 0; i < 4; ++i) {
                int r = 16 * j + lhi * 4 + i;
                ps[r][w] = se[j][i]; pe[r][w] = ee[j][i]; pb[r][w] = bbv[j][i];
            }
    }
    __syncthreads();
    if (tid < 64) {
        float s = 0.f, e = NEGV, bq = NEGV;
#pragma unroll
        for (int w0 = 0; w0 < 8; ++w0) {
            s += ps[tid][w0];
            e = fmaxf(e, pe[tid][w0]);
            bq = fmaxf(bq, pb[tid][w0]);
        }
        float lse = __logf(s);
        int gid = blk * 64 + tid;
        if (gid < RTOT) {
            blank_buf[gid] = bq - lse;
            emit_buf[gid]  = e - lse;
        }
    }
}

// ---------------- fused DPs: blocks 0-3 RNNT (wavefront), 4-7 CTC ----------
__global__ void dp_fused(const float* __restrict__ blank_buf, const float* __restrict__ emit_buf,
                         const float* __restrict__ ctc_logits, const float* __restrict__ ctc_lse,
                         const int* __restrict__ target, const int* __restrict__ frame_len,
                         const int* __restrict__ tgt_len,
                         float* __restrict__ loss_rnnt, float* __restrict__ loss_ctc)
{
    __shared__ float sm[20800];
    const int bid = blockIdx.x;
    const int u = threadIdx.x;   // 64

    if (bid < 4) {
        // ---- RNNT anti-diagonal wavefront: lane u owns column u ----
        const int b = bid;
        float2* pk = (float2*)sm;    // [52][200]: (blank[t][u], emit[t][u]) at pk[u*200+t]
        for (int i = u; i < U1 * TT; i += 64) {
            int uu = i / TT, t = i - uu * TT;
            float bl = blank_buf[(b * TT + t) * U1 + uu];
            float em = emit_buf[(b * TT + t) * U1 + uu];
            pk[uu * TT + t] = make_float2(bl, em);
        }
        __syncthreads();
        const int fl = frame_len[b], tl = tgt_len[b];
        float A = (u == 0) ? 0.f : NEGV;     // alpha[0][0]=0
        if (fl == 1 && tl == 0 && u == 0) loss_rnnt[b] = -(A + pk[0].x);
        for (int d = 1; d <= TT + U1 - 2; ++d) {
            int x = d - 1 - u;
            int xc = min(max(x, 0), TT - 1);
            int uc = min(u, U1);
            float2 be = pk[uc * TT + xc];
            float vshare = A + be.y;
            float left = __shfl_up(vshare, 1);
            if (u == 0) left = NEGV;
            int t_new = d - u;
            if (u < U1 && t_new >= 0 && t_new < TT) {
                float up = (t_new >= 1) ? (A + be.x) : NEGV;
                A = lae(up, left);
                if (t_new == fl - 1 && u == tl)
                    loss_rnnt[b] = -(A + pk[u * TT + t_new].x);
            }
        }
    } else {
        // ---- CTC: 2 states per lane, 200 serial t-steps ----
        const int b = bid - 4;
        float* lpE  = sm;
        float* lseB = sm + 200;
        float (*lpO)[52] = (float(*)[52])(sm + 400);
        for (int idx = u; idx < 200; idx += 64) {
            int bt = b * 200 + idx;
            float ls = ctc_lse[bt];
            lseB[idx] = ls;
            lpE[idx] = ctc_logits[(size_t)bt * VV + (VV - 1)] - ls;
        }
        for (int idx = u; idx < 200 * 50; idx += 64) {
            int t = idx / 50, uu = idx - t * 50;
            int tok = target[b * UU + uu];
            lpO[t][uu] = ctc_logits[(size_t)(b * 200 + t) * VV + tok];
        }
        __syncthreads();
        const int fl = frame_len[b], tl = tgt_len[b];
        bool skip = false;
        if (u >= 1 && u < UU) skip = (target[b * UU + u] != target[b * UU + u - 1]);

        float old_e = (u == 0) ? lpE[0] : NEGV;
        float old_o = (u == 0) ? (lpO[0][0] - lseB[0]) : NEGV;
        if (fl == 1 && u == 0) {
            float a_last = __shfl(old_e, tl);
            float a_prev = __shfl(old_o, tl - 1);
            loss_ctc[b] = -lae(a_last, a_prev);
        }
        for (int t = 1; t < 200; ++t) {
            float prev_o = __shfl_up(old_o, 1);
            if (u == 0) prev_o = NEGV;
            float lp_e = lpE[t];
            float lp_o = (u < UU) ? (lpO[t][u] - lseB[t]) : NEGV;
            float ne = lp_e + lae(old_e, prev_o);
            float no = lp_o + lae3(old_o, old_e, skip ? prev_o : NEGV);
            if (u > 50) ne = NEGV;
            if (u >= 50) no = NEGV;
            old_e = ne; old_o = no;
            if (t == fl - 1) {
                float a_last = __shfl(old_e, tl);
                float a_prev = __shfl(old_o, tl - 1);
                if (u == 0) loss_ctc[b] = -lae(a_last, a_prev);
            }
        }
    }
}

// ---------------- final combine -------------------------------------------
__global__ void combine(const float* __restrict__ lr, const float* __restrict__ lc,
                        float* __restrict__ out)
{
    float r = 0.25f * (lr[0] + lr[1] + lr[2] + lr[3]);
    float c = 0.25f * (lc[0] + lc[1] + lc[2] + lc[3]);
    out[0] = r + 0.3f * c;
}

extern "C" void kernel_launch(void* const* d_in, const int* in_sizes, int n_in,
                              void* d_out, int out_size, void* d_ws, size_t ws_size,
                              hipStream_t stream)
{
    const float* x_enc   = (const float*)d_in[0];
    const float* x_dec   = (const float*)d_in[1];
    const int*   target  = (const int*)d_in[2];
    const int*   frame_l = (const int*)d_in[3];
    const int*   tgt_l   = (const int*)d_in[4];
    const float* W_ctc   = (const float*)d_in[5];
    const float* b_ctc   = (const float*)d_in[6];
    const float* W_enc   = (const float*)d_in[7];
    const float* W_pred  = (const float*)d_in[8];
    const float* b_joint = (const float*)d_in[9];
    const float* W_out   = (const float*)d_in[10];
    const float* b_out   = (const float*)d_in[11];
    float* out = (float*)d_out;

    float* wsf        = (float*)d_ws;
    float* enc_proj   = wsf;                       // 512000
    float* pred_proj  = wsf + 512000;              // 130560
    float* ctc_logits = wsf + 642560;              // 819200
    float* ctc_lse    = wsf + 1461760;             // 832
    float* blank_buf  = wsf + 1462592;             // 40832
    float* emit_buf   = wsf + 1503424;             // 40832
    float* loss_rnnt  = wsf + 1544256;             // 4
    float* loss_ctc   = wsf + 1544260;             // 4 (+pad to 1544272)
    bf16_t* FOut  = (bf16_t*)(wsf + 1544272);      // 655360 bf16
    bf16_t* FEnc  = (bf16_t*)(wsf + 1871952);      // 327680 bf16
    bf16_t* FPred = (bf16_t*)(wsf + 2035792);      // 409600 bf16
    bf16_t* FCtc  = (bf16_t*)(wsf + 2240592);      // 524288 bf16

    pack_all<<<7488, 256, 0, stream>>>(W_out, W_enc, W_pred, W_ctc, FOut, FEnc, FPred, FCtc);
    mfma_gemm3<<<30, 512, 0, stream>>>(x_enc, x_dec, FEnc, FPred, FCtc, b_ctc,
                                       enc_proj, pred_proj, ctc_logits, ctc_lse);
    joint_gemm<<<RPAD / 64, 512, 0, stream>>>(enc_proj, pred_proj, b_joint, FOut, b_out,
                                              target, blank_buf, emit_buf);
    dp_fused<<<8, 64, 0, stream>>>(blank_buf, emit_buf, ctc_logits, ctc_lse,
                                   target, frame_l, tgt_l, loss_rnnt, loss_ctc);
    combine<<<1, 1, 0, stream>>>(loss_rnnt, loss_ctc, out);
}

// Round 6
// 196.232 us; speedup vs baseline: 1.2338x; 1.2338x over previous
//
#include <hip/hip_runtime.h>
#include <hip/hip_bf16.h>

typedef __bf16 bf16_t;
typedef __attribute__((ext_vector_type(4))) __bf16 bf16x4;
typedef __attribute__((ext_vector_type(8))) __bf16 bf16x8;
typedef __attribute__((ext_vector_type(4))) float f32x4;

#define NEGV (-1e30f)

// Problem constants
#define BB 4
#define TT 200
#define UU 50
#define U1 51
#define VV 1024
#define DD 512
#define HH 640
#define RTOT (BB*TT*U1)      // 40800
#define RPAD 40832           // 638*64
#define SS 101

__device__ __forceinline__ float lae(float a, float b) {
    float mx = fmaxf(a, b);
    return mx + __logf(__expf(a - mx) + __expf(b - mx));
}
__device__ __forceinline__ float lae3(float a, float b, float c) {
    float mx = fmaxf(fmaxf(a, b), c);
    return mx + __logf(__expf(a - mx) + __expf(b - mx) + __expf(c - mx));
}
__device__ __forceinline__ float tanh_fast(float x) {
    float ex = __expf(2.f * x);
    return 1.f - 2.f / (ex + 1.f);
}

// ---------------- pack fp32 (K x N) weight into bf16 MFMA B-fragment order.
__device__ __forceinline__ void pack_seg(const float* __restrict__ W, bf16_t* __restrict__ Wf,
                                         int e, int K32, int N)
{
    int j  = e & 7;
    int l  = (e >> 3) & 63;
    int kk = (e >> 9) % K32;
    int nt = e / (K32 * 512);
    int v = nt * 16 + (l & 15);
    int k = kk * 32 + ((l >> 4) << 2) + (j & 3) + ((j >> 2) << 4);
    Wf[e] = (bf16_t)W[(size_t)k * N + v];
}

__global__ void pack_all(const float* __restrict__ Wout, const float* __restrict__ Wenc,
                         const float* __restrict__ Wpred, const float* __restrict__ Wctc,
                         bf16_t* __restrict__ FOut, bf16_t* __restrict__ FEnc,
                         bf16_t* __restrict__ FPred, bf16_t* __restrict__ FCtc)
{
    int e = blockIdx.x * 256 + threadIdx.x;
    if (e < 655360) { pack_seg(Wout, FOut, e, 20, 1024); return; }
    e -= 655360;
    if (e < 327680) { pack_seg(Wenc, FEnc, e, 16, 640); return; }
    e -= 327680;
    if (e < 409600) { pack_seg(Wpred, FPred, e, 20, 640); return; }
    e -= 409600;
    pack_seg(Wctc, FCtc, e, 16, 1024);
}

// ---------------- generic MFMA GEMM: C = A(MxK fp32) @ Wf(packed bf16) -----
template<int K32, int L, bool LSE>
__device__ void gemm_dev(const float* __restrict__ A, int M, int rowbase, int K,
                         const bf16_t* __restrict__ Wf, const float* __restrict__ bias,
                         float* __restrict__ C, float* __restrict__ lse_out, int N,
                         bf16_t* Atile, float (*ps)[8])
{
    const int tid = threadIdx.x;
    // build A tile in fragment order; thread == fragment -> contiguous 16B
    // LDS writes (conflict-free ds_write_b128). 256*K32 frags / 512 thr.
#pragma unroll
    for (int it = 0; it < K32 / 2; ++it) {
        int fi = it * 512 + tid;
        int l = fi & 63, jk = fi >> 6;
        int j = jk / K32, kk = jk - j * K32;
        int row = rowbase + j * 16 + (l & 15);
        if (row > M - 1) row = M - 1;
        int c0 = kk * 32 + ((l >> 4) << 2);
        const float4 a0 = *(const float4*)&A[(size_t)row * K + c0];
        const float4 a1 = *(const float4*)&A[(size_t)row * K + c0 + 16];
        bf16x8 v;
        v[0] = (bf16_t)a0.x; v[1] = (bf16_t)a0.y; v[2] = (bf16_t)a0.z; v[3] = (bf16_t)a0.w;
        v[4] = (bf16_t)a1.x; v[5] = (bf16_t)a1.y; v[6] = (bf16_t)a1.z; v[7] = (bf16_t)a1.w;
        *(bf16x8*)&Atile[(size_t)fi * 8] = v;
    }
    __syncthreads();

    const int l = tid & 63, w = tid >> 6;
    const int lrow = l & 15, lhi = l >> 4;

    f32x4 acc[4][L];
#pragma unroll
    for (int j = 0; j < 4; ++j)
#pragma unroll
        for (int li = 0; li < L; ++li) acc[j][li] = f32x4{0.f, 0.f, 0.f, 0.f};

    for (int kk = 0; kk < K32; ++kk) {
        bf16x8 a[4];
#pragma unroll
        for (int j = 0; j < 4; ++j)
            a[j] = *(const bf16x8*)&Atile[(size_t)(((j * K32 + kk) * 64 + l) * 8)];
#pragma unroll
        for (int li = 0; li < L; ++li) {
            bf16x8 b = *(const bf16x8*)&Wf[(size_t)(((w * L + li) * K32 + kk) * 64 + l) * 8];
#pragma unroll
            for (int j = 0; j < 4; ++j)
                acc[j][li] = __builtin_amdgcn_mfma_f32_16x16x32_bf16(a[j], b, acc[j][li], 0, 0, 0);
        }
    }

    float se[4][4];
    if (LSE) {
#pragma unroll
        for (int j = 0; j < 4; ++j)
#pragma unroll
            for (int i = 0; i < 4; ++i) se[j][i] = 0.f;
    }
#pragma unroll
    for (int j = 0; j < 4; ++j)
#pragma unroll
        for (int li = 0; li < L; ++li) {
            int col = (w * L + li) * 16 + lrow;
            float bv = bias ? bias[col] : 0.f;
#pragma unroll
            for (int i = 0; i < 4; ++i) {
                int grow = rowbase + 16 * j + lhi * 4 + i;
                float x = acc[j][li][i] + bv;
                if (grow < M) C[(size_t)grow * N + col] = x;
                if (LSE) se[j][i] += __expf(x);
            }
        }
    if (LSE) {
#pragma unroll
        for (int d = 1; d < 16; d <<= 1)
#pragma unroll
            for (int j = 0; j < 4; ++j)
#pragma unroll
                for (int i = 0; i < 4; ++i) se[j][i] += __shfl_xor(se[j][i], d);
        if (lrow == 0) {
#pragma unroll
            for (int j = 0; j < 4; ++j)
#pragma unroll
                for (int i = 0; i < 4; ++i) ps[16 * j + lhi * 4 + i][w] = se[j][i];
        }
        __syncthreads();
        if (tid < 64) {
            float s = 0.f;
#pragma unroll
            for (int w0 = 0; w0 < 8; ++w0) s += ps[tid][w0];
            int grow = rowbase + tid;
            if (grow < M) lse_out[grow] = __logf(s);
        }
    }
}

__global__ __launch_bounds__(512)
void mfma_gemm3(const float* __restrict__ x_enc, const float* __restrict__ x_dec,
                const bf16_t* __restrict__ FEnc, const bf16_t* __restrict__ FPred,
                const bf16_t* __restrict__ FCtc, const float* __restrict__ b_ctc,
                float* __restrict__ enc_proj, float* __restrict__ pred_proj,
                float* __restrict__ ctc_logits, float* __restrict__ ctc_lse)
{
    __shared__ bf16_t Atile[40960];
    __shared__ float ps[64][8];
    int blk = blockIdx.x;
    if (blk < 13)
        gemm_dev<16, 5, false>(x_enc, 800, blk * 64, 512, FEnc, nullptr, enc_proj, nullptr, 640, Atile, ps);
    else if (blk < 17)
        gemm_dev<20, 5, false>(x_dec, 204, (blk - 13) * 64, 640, FPred, nullptr, pred_proj, nullptr, 640, Atile, ps);
    else
        gemm_dev<16, 8, true>(x_enc, 800, (blk - 17) * 64, 512, FCtc, b_ctc, ctc_logits, ctc_lse, 1024, Atile, ps);
}

// ---------------- fused joint build + MFMA GEMM + row-LSE + gather ---------
__global__ __launch_bounds__(512)
void joint_gemm(const float* __restrict__ enc,   // (800,640)
                const float* __restrict__ pred,  // (204,640)
                const float* __restrict__ bj,    // (640)
                const bf16_t* __restrict__ Wf,   // packed (K32=20, NT=64)
                const float* __restrict__ bo,    // (1024)
                const int* __restrict__ target,  // (4,50)
                float* __restrict__ blank_buf, float* __restrict__ emit_buf)
{
    __shared__ bf16_t Afrag[40960];              // 64 rows x 640 K, frag order
    __shared__ int rowBT[64], rowBU[64], rowTG[64];
    __shared__ float ps[64][8], pe[64][8], pb[64][8];
    const int tid = threadIdx.x;
    const int blk = blockIdx.x;

    const int l = tid & 63, w = tid >> 6;
    const int lrow = l & 15, lhi = l >> 4;

    if (tid < 64) {
        int r = blk * 64 + tid; if (r > RTOT - 1) r = RTOT - 1;
        int b = r / (TT * U1); int rem = r - b * (TT * U1);
        int t = rem / U1;      int u = rem - t * U1;
        rowBT[tid] = b * TT + t;
        rowBU[tid] = b * U1 + u;
        rowTG[tid] = (u < UU) ? target[b * UU + u] : -1;
    }
    __syncthreads();

    // build tanh(enc+pred+bj) tile; thread == fragment -> contiguous 16B
    // LDS writes (conflict-free). 5120 fragments / 512 threads = 10 iters.
#pragma unroll
    for (int it = 0; it < 10; ++it) {
        int fi = it * 512 + tid;
        int ll = fi & 63, jk = fi >> 6;
        int j = jk / 20, kk = jk - j * 20;
        int row = j * 16 + (ll & 15);
        int c0 = kk * 32 + ((ll >> 4) << 2);
        const float4 e0 = *(const float4*)&enc[(size_t)rowBT[row] * HH + c0];
        const float4 e1 = *(const float4*)&enc[(size_t)rowBT[row] * HH + c0 + 16];
        const float4 p0 = *(const float4*)&pred[(size_t)rowBU[row] * HH + c0];
        const float4 p1 = *(const float4*)&pred[(size_t)rowBU[row] * HH + c0 + 16];
        const float4 q0 = *(const float4*)&bj[c0];
        const float4 q1 = *(const float4*)&bj[c0 + 16];
        bf16x8 v;
        v[0] = (bf16_t)tanh_fast(e0.x + p0.x + q0.x);
        v[1] = (bf16_t)tanh_fast(e0.y + p0.y + q0.y);
        v[2] = (bf16_t)tanh_fast(e0.z + p0.z + q0.z);
        v[3] = (bf16_t)tanh_fast(e0.w + p0.w + q0.w);
        v[4] = (bf16_t)tanh_fast(e1.x + p1.x + q1.x);
        v[5] = (bf16_t)tanh_fast(e1.y + p1.y + q1.y);
        v[6] = (bf16_t)tanh_fast(e1.z + p1.z + q1.z);
        v[7] = (bf16_t)tanh_fast(e1.w + p1.w + q1.w);
        *(bf16x8*)&Afrag[(size_t)fi * 8] = v;
    }
    __syncthreads();

    f32x4 acc[4][8];
#pragma unroll
    for (int j = 0; j < 4; ++j)
#pragma unroll
        for (int li = 0; li < 8; ++li) acc[j][li] = f32x4{0.f, 0.f, 0.f, 0.f};

    const bf16_t* Bp = &Wf[(size_t)((w * 8 * 20) * 64 + l) * 8];

    // K loop: start offset rotated per block so concurrent blocks don't
    // march through identical Wf addresses in lockstep (L2 channel
    // decorrelation); fp32 accumulate order change only.
    const int rot = blk % 20;
    for (int kk0 = 0; kk0 < 20; ++kk0) {
        int kk = kk0 + rot; if (kk >= 20) kk -= 20;
        bf16x8 a[4];
#pragma unroll
        for (int j = 0; j < 4; ++j)
            a[j] = *(const bf16x8*)&Afrag[(size_t)(((j * 20 + kk) * 64 + l) * 8)];
#pragma unroll
        for (int li = 0; li < 8; ++li) {
            bf16x8 b = *(const bf16x8*)(Bp + (size_t)li * 10240 + (size_t)kk * 512);
#pragma unroll
            for (int j = 0; j < 4; ++j)
                acc[j][li] = __builtin_amdgcn_mfma_f32_16x16x32_bf16(a[j], b, acc[j][li], 0, 0, 0);
        }
    }

    int tg[4][4];
#pragma unroll
    for (int j = 0; j < 4; ++j)
#pragma unroll
        for (int i = 0; i < 4; ++i) tg[j][i] = rowTG[16 * j + lhi * 4 + i];

    float se[4][4], ee[4][4], bbv[4][4];
#pragma unroll
    for (int j = 0; j < 4; ++j)
#pragma unroll
        for (int i = 0; i < 4; ++i) { se[j][i] = 0.f; ee[j][i] = NEGV; bbv[j][i] = NEGV; }

#pragma unroll
    for (int li = 0; li < 8; ++li) {
        int col = (w * 8 + li) * 16 + lrow;
        float bv = bo[col];
#pragma unroll
        for (int j = 0; j < 4; ++j)
#pragma unroll
            for (int i = 0; i < 4; ++i) {
                float x = acc[j][li][i] + bv;
                se[j][i] += __expf(x);
                if (col == tg[j][i]) ee[j][i] = x;
                if (col == VV - 1) bbv[j][i] = x;
            }
    }
#pragma unroll
    for (int d = 1; d < 16; d <<= 1)
#pragma unroll
        for (int j = 0; j < 4; ++j)
#pragma unroll
            for (int i = 0; i < 4; ++i) {
                se[j][i] += __shfl_xor(se[j][i], d);
                ee[j][i] = fmaxf(ee[j][i], __shfl_xor(ee[j][i], d));
                bbv[j][i] = fmaxf(bbv[j][i], __shfl_xor(bbv[j][i], d));
            }
    if (lrow == 0) {
#pragma unroll
        for (int j = 0; j < 4; ++j)
#pragma unroll
            for (int i = 0; i < 4; ++i) {
                int r = 16 * j + lhi * 4 + i;
                ps[r][w] = se[j][i]; pe[r][w] = ee[j][i]; pb[r][w] = bbv[j][i];
            }
    }
    __syncthreads();
    if (tid < 64) {
        float s = 0.f, e = NEGV, bq = NEGV;
#pragma unroll
        for (int w0 = 0; w0 < 8; ++w0) {
            s += ps[tid][w0];
            e = fmaxf(e, pe[tid][w0]);
            bq = fmaxf(bq, pb[tid][w0]);
        }
        float lse = __logf(s);
        int gid = blk * 64 + tid;
        if (gid < RTOT) {
            blank_buf[gid] = bq - lse;
            emit_buf[gid]  = e - lse;
        }
    }
}

// ---------------- fused DPs: blocks 0-3 RNNT (wavefront), 4-7 CTC ----------
__global__ void dp_fused(const float* __restrict__ blank_buf, const float* __restrict__ emit_buf,
                         const float* __restrict__ ctc_logits, const float* __restrict__ ctc_lse,
                         const int* __restrict__ target, const int* __restrict__ frame_len,
                         const int* __restrict__ tgt_len,
                         float* __restrict__ loss_rnnt, float* __restrict__ loss_ctc)
{
    __shared__ float sm[20800];
    const int bid = blockIdx.x;
    const int u = threadIdx.x;   // 64

    if (bid < 4) {
        // ---- RNNT anti-diagonal wavefront: lane u owns column u ----
        const int b = bid;
        float2* pk = (float2*)sm;    // [52][200]: (blank[t][u], emit[t][u]) at pk[u*200+t]
        for (int i = u; i < U1 * TT; i += 64) {
            int uu = i / TT, t = i - uu * TT;
            float bl = blank_buf[(b * TT + t) * U1 + uu];
            float em = emit_buf[(b * TT + t) * U1 + uu];
            pk[uu * TT + t] = make_float2(bl, em);
        }
        __syncthreads();
        const int fl = frame_len[b], tl = tgt_len[b];
        float A = (u == 0) ? 0.f : NEGV;     // alpha[0][0]=0
        if (fl == 1 && tl == 0 && u == 0) loss_rnnt[b] = -(A + pk[0].x);
        for (int d = 1; d <= TT + U1 - 2; ++d) {
            int x = d - 1 - u;
            int xc = min(max(x, 0), TT - 1);
            int uc = min(u, U1);
            float2 be = pk[uc * TT + xc];
            float vshare = A + be.y;
            float left = __shfl_up(vshare, 1);
            if (u == 0) left = NEGV;
            int t_new = d - u;
            if (u < U1 && t_new >= 0 && t_new < TT) {
                float up = (t_new >= 1) ? (A + be.x) : NEGV;
                A = lae(up, left);
                if (t_new == fl - 1 && u == tl)
                    loss_rnnt[b] = -(A + pk[u * TT + t_new].x);
            }
        }
    } else {
        // ---- CTC: 2 states per lane, 200 serial t-steps ----
        const int b = bid - 4;
        float* lpE  = sm;
        float* lseB = sm + 200;
        float (*lpO)[52] = (float(*)[52])(sm + 400);
        for (int idx = u; idx < 200; idx += 64) {
            int bt = b * 200 + idx;
            float ls = ctc_lse[bt];
            lseB[idx] = ls;
            lpE[idx] = ctc_logits[(size_t)bt * VV + (VV - 1)] - ls;
        }
        for (int idx = u; idx < 200 * 50; idx += 64) {
            int t = idx / 50, uu = idx - t * 50;
            int tok = target[b * UU + uu];
            lpO[t][uu] = ctc_logits[(size_t)(b * 200 + t) * VV + tok];
        }
        __syncthreads();
        const int fl = frame_len[b], tl = tgt_len[b];
        bool skip = false;
        if (u >= 1 && u < UU) skip = (target[b * UU + u] != target[b * UU + u - 1]);

        float old_e = (u == 0) ? lpE[0] : NEGV;
        float old_o = (u == 0) ? (lpO[0][0] - lseB[0]) : NEGV;
        if (fl == 1 && u == 0) {
            float a_last = __shfl(old_e, tl);
            float a_prev = __shfl(old_o, tl - 1);
            loss_ctc[b] = -lae(a_last, a_prev);
        }
        for (int t = 1; t < 200; ++t) {
            float prev_o = __shfl_up(old_o, 1);
            if (u == 0) prev_o = NEGV;
            float lp_e = lpE[t];
            float lp_o = (u < UU) ? (lpO[t][u] - lseB[t]) : NEGV;
            float ne = lp_e + lae(old_e, prev_o);
            float no = lp_o + lae3(old_o, old_e, skip ? prev_o : NEGV);
            if (u > 50) ne = NEGV;
            if (u >= 50) no = NEGV;
            old_e = ne; old_o = no;
            if (t == fl - 1) {
                float a_last = __shfl(old_e, tl);
                float a_prev = __shfl(old_o, tl - 1);
                if (u == 0) loss_ctc[b] = -lae(a_last, a_prev);
            }
        }
    }
}

// ---------------- final combine -------------------------------------------
__global__ void combine(const float* __restrict__ lr, const float* __restrict__ lc,
                        float* __restrict__ out)
{
    float r = 0.25f * (lr[0] + lr[1] + lr[2] + lr[3]);
    float c = 0.25f * (lc[0] + lc[1] + lc[2] + lc[3]);
    out[0] = r + 0.3f * c;
}

extern "C" void kernel_launch(void* const* d_in, const int* in_sizes, int n_in,
                              void* d_out, int out_size, void* d_ws, size_t ws_size,
                              hipStream_t stream)
{
    const float* x_enc   = (const float*)d_in[0];
    const float* x_dec   = (const float*)d_in[1];
    const int*   target  = (const int*)d_in[2];
    const int*   frame_l = (const int*)d_in[3];
    const int*   tgt_l   = (const int*)d_in[4];
    const float* W_ctc   = (const float*)d_in[5];
    const float* b_ctc   = (const float*)d_in[6];
    const float* W_enc   = (const float*)d_in[7];
    const float* W_pred  = (const float*)d_in[8];
    const float* b_joint = (const float*)d_in[9];
    const float* W_out   = (const float*)d_in[10];
    const float* b_out   = (const float*)d_in[11];
    float* out = (float*)d_out;

    float* wsf        = (float*)d_ws;
    float* enc_proj   = wsf;                       // 512000
    float* pred_proj  = wsf + 512000;              // 130560
    float* ctc_logits = wsf + 642560;              // 819200
    float* ctc_lse    = wsf + 1461760;             // 832
    float* blank_buf  = wsf + 1462592;             // 40832
    float* emit_buf   = wsf + 1503424;             // 40832
    float* loss_rnnt  = wsf + 1544256;             // 4
    float* loss_ctc   = wsf + 1544260;             // 4 (+pad to 1544272)
    bf16_t* FOut  = (bf16_t*)(wsf + 1544272);      // 655360 bf16
    bf16_t* FEnc  = (bf16_t*)(wsf + 1871952);      // 327680 bf16
    bf16_t* FPred = (bf16_t*)(wsf + 2035792);      // 409600 bf16
    bf16_t* FCtc  = (bf16_t*)(wsf + 2240592);      // 524288 bf16

    pack_all<<<7488, 256, 0, stream>>>(W_out, W_enc, W_pred, W_ctc, FOut, FEnc, FPred, FCtc);
    mfma_gemm3<<<30, 512, 0, stream>>>(x_enc, x_dec, FEnc, FPred, FCtc, b_ctc,
                                       enc_proj, pred_proj, ctc_logits, ctc_lse);
    joint_gemm<<<RPAD / 64, 512, 0, stream>>>(enc_proj, pred_proj, b_joint, FOut, b_out,
                                              target, blank_buf, emit_buf);
    dp_fused<<<8, 64, 0, stream>>>(blank_buf, emit_buf, ctc_logits, ctc_lse,
                                   target, frame_l, tgt_l, loss_rnnt, loss_ctc);
    combine<<<1, 1, 0, stream>>>(loss_rnnt, loss_ctc, out);
}